// Round 6
// baseline (260.506 us; speedup 1.0000x reference)
//
#include <hip/hip_runtime.h>
#include <hip/hip_cooperative_groups.h>
#include <hip/hip_fp16.h>
#include <math.h>

namespace cg = cooperative_groups;

#define NPATH 1536
#define SEGS  65        // 0..64 active-channel counts
#define NB    160
#define NA    160
#define CW    32        // chunks (waves) per (z,a)
#define PPW   5         // pairs per wave = NB/CW

// d_ws layout:
//   [0, 21.3MB)  PC[zb][seg][256 u32]  — packed {fp16 slope | fp16 icpt}
//   [21.3MB, +2.6MB) SWB2 — feature-independent per-slot segment table:
//     float4 index (T = tg*16+tl, s = k*16+sgrp, j = v-pair):
//       flat4 = (((tg*5 + k)*8 + j)*16 + sgrp)*16 + tl
//     float4 = {sw(v=2j), sb(2j), sw(2j+1), sb(2j+1)}  (k=4: only sgrp=0 used)
#define PC_U32S   (320 * SEGS * 256)            // 5,324,800 u32
#define SWB_OFF   PC_U32S                        // float offset into ws

__device__ float dg_thr[64];                     // fallback path only

#define SCL_A 0.17677669529663687f
#define SCL_B 0.6266570686577502f
#define SCL_C 0.2558286876965162f
#define SCL_D 0.125f
#define SCL_E 0.3133285343288751f
#define SCL_F 0.7674950309598664f

static __device__ __forceinline__ void slot_map(int t, int& pbase, int& pstr,
                                                int& comp, float& scl) {
    int lane4 = t >> 2, j = t & 3;
    pbase = 0; pstr = 1; comp = -1; scl = 0.0f;
    if (lane4 < 16) {
        if (j == 0) { pbase = lane4 * 16;       scl = SCL_A; }
        else        { pbase = 256 + lane4 * 16; comp = j - 1; scl = SCL_B; }
    } else {
        int lu = lane4 - 16, u = lu / 3, part = lu - u * 3;
        if (part == 0) {
            if (j == 0) { pbase = 512 + u * 16;                       scl = SCL_C; }
            else        { pbase = 768 + u * 48; pstr = 3; comp = j - 1; scl = SCL_D; }
        } else if (part == 1) {
            if (j < 3)  { pbase = 768 + u * 48 + 1; pstr = 3; comp = j; scl = SCL_E; }
        } else {
            if (j < 3)  { pbase = 768 + u * 48 + 2; pstr = 3; comp = j; scl = SCL_F; }
        }
    }
}

static __device__ __forceinline__ float rcomb(unsigned int v, float r) {
    union { unsigned int u; __half2 h; } cv; cv.u = v;
    return fmaf(r, __low2float(cv.h), __high2float(cv.h));
}

// ===================== fused cooperative kernel =====================
// 640 blocks x 256 threads, 3 blocks/CU co-resident.
// Phase A: blocks 0..255 build SWB2 (one slot each); 256..335 zero out.
// Phase B: all 640 blocks: PC[zb][s][T] GEMM (tg = bid&15, zt = bid>>4, 8 zb).
// Phase C: 4-iteration grid-stride of the k_main body (bt = it*640 + bid).
__global__ __launch_bounds__(256, 3) void k_all(const float* __restrict__ feat,
                                                const float* __restrict__ geom,
                                                const float* __restrict__ mask,
                                                const float* __restrict__ W1,
                                                const float* __restrict__ b1,
                                                const float* __restrict__ W2,
                                                const float* __restrict__ b2,
                                                float* __restrict__ ws,
                                                float* __restrict__ out) {
    cg::grid_group grid = cg::this_grid();
    int bid = blockIdx.x, tid = threadIdx.x;

    __shared__ float  tvS[64];
    __shared__ float4 chS[64];              // {wPos, wNeg, bSel, bUnsel}
    __shared__ int    rkS[64];
    __shared__ int    ordS[64];
    __shared__ float  dwS[64], dbS[64], b2S[16];
    __shared__ float  W2t[16][65];          // pad 65
    __shared__ __align__(16) float fS[8][64];
    __shared__ float  sAcc[4][64];

    unsigned int* PC = (unsigned int*)ws;

    // ---------------- phase A ----------------
    if (bid < 256) {
        int t = bid;
        if (tid < 64) {
            float w = W1[tid], bb = b1[tid];
            tvS[tid] = (w != 0.0f) ? (-bb / w) : __builtin_inff();
        }
        __syncthreads();
        if (tid < 64) {
            float mine = tvS[tid];
            int rank = 0;
            for (int j2 = 0; j2 < 64; ++j2) {
                float o = tvS[j2];
                rank += (o < mine || (o == mine && j2 < tid)) ? 1 : 0;
            }
            float w = W1[tid], bb = b1[tid];
            // sel (= rank < s): threshold-passed set. w>0 active iff sel;
            // w<0 active iff !sel; w==0 active iff b>0 (always !sel).
            chS[tid] = make_float4((w > 0.0f) ? w : 0.0f,
                                   (w < 0.0f) ? w : 0.0f,
                                   (w > 0.0f) ? bb : 0.0f,
                                   (w < 0.0f) ? bb : ((w == 0.0f && bb > 0.0f) ? bb : 0.0f));
            rkS[tid] = rank;
            ordS[rank] = tid;
            dwS[rank]  = fabsf(w);
            dbS[rank]  = (w > 0.0f) ? bb : ((w < 0.0f) ? -bb : 0.0f);
        }
        int pbase, pstr, comp; float scl;
        slot_map(t, pbase, pstr, comp, scl);
        (void)comp;
        int cs = tid >> 2, vq = tid & 3;    // 16 c-rows per wave-instr
        #pragma unroll
        for (int i = 0; i < 4; ++i) {
            int v = vq * 4 + i;
            W2t[v][cs] = scl * W2[(size_t)cs * NPATH + pbase + v * pstr];
        }
        if (tid < 16) b2S[tid] = scl * b2[pbase + tid * pstr];
        __syncthreads();

        int v = tid & 15, sq = tid >> 4;    // 16 v x 16 s-quads
        int s0 = sq * 4;
        float sw = 0.0f, sb = 0.0f;
        #pragma unroll 8
        for (int cc = 0; cc < 64; ++cc) {
            float  w2 = W2t[v][cc];
            float4 ch = chS[cc];
            bool sel = rkS[cc] < s0;
            sw = fmaf(sel ? ch.x : ch.y, w2, sw);
            sb = fmaf(sel ? ch.z : ch.w, w2, sb);
        }
        sb += b2S[v];

        int tg = t >> 4, tl = t & 15, jj = v >> 1, half = v & 1;
        float2* swb2 = (float2*)(ws + SWB_OFF);
        int ns = (sq == 15) ? 5 : 4;        // sq 15 also writes s=64
        for (int i = 0; i < ns; ++i) {
            int s = s0 + i, k = s >> 4, sg = s & 15;
            int flat4 = (((tg * 5 + k) * 8 + jj) * 16 + sg) * 16 + tl;
            swb2[flat4 * 2 + half] = make_float2(sw, sb);
            if (i + 1 < ns) {
                float w2s = W2t[v][ordS[s]];
                sw = fmaf(dwS[s], w2s, sw);
                sb = fmaf(dbS[s], w2s, sb);
            }
        }
    } else if (bid < 336) {                 // 80 blocks x 256 = 20480 floats
        out[(bid - 336 + 80) % 80 * 256 + tid] = 0.0f;
    }

    grid.sync();

    // ---------------- phase B ----------------
    {
        int tg = bid & 15, zt = bid >> 4;   // zt 0..39, zb-tile 8
        int zb0 = zt * 8;
        #pragma unroll
        for (int i = 0; i < 2; ++i) {
            int idx = tid + i * 256;        // 512 floats
            int row = idx >> 6, fi = idx & 63;
            float val = feat[(size_t)(zb0 + row) * 64 + fi];
            int dest;
            if (fi < 16) dest = fi;
            else { int q = (fi - 16) / 3, c3 = (fi - 16) - 3 * q; dest = (c3 + 1) * 16 + q; }
            fS[row][dest] = val;
        }
        __syncthreads();

        int tl = tid & 15, sgrp = tid >> 4;
        int T = tg * 16 + tl;
        int pbase, pstr, comp; float scl;
        slot_map(T, pbase, pstr, comp, scl);
        (void)pbase; (void)pstr; (void)scl;
        const float* fb = &fS[0][(comp + 1) * 16];
        const float4* swb = (const float4*)(ws + SWB_OFF);

        for (int k = 0; k < 5; ++k) {
            int s = k * 16 + sgrp;
            if (s >= SEGS) break;            // only k=4, sgrp>0 exits
            int base4 = (((tg * 5 + k) * 8) * 16 + sgrp) * 16 + tl;
            float4 q0 = swb[base4];
            float4 q1 = swb[base4 + 256], q2 = swb[base4 + 512], q3 = swb[base4 + 768];
            float4 q4 = swb[base4 + 1024], q5 = swb[base4 + 1280];
            float4 q6 = swb[base4 + 1536], q7 = swb[base4 + 1792];
            unsigned int* op = PC + (size_t)zb0 * (SEGS * 256) + (size_t)s * 256 + T;
            #pragma unroll 2
            for (int zb = 0; zb < 8; ++zb) {
                const float4* fp = (const float4*)(fb + zb * 64);
                float4 f0 = fp[0], f1 = fp[1], f2 = fp[2], f3 = fp[3];
                float sw = q0.x * f0.x,          sb = q0.y * f0.x;
                sw = fmaf(q0.z, f0.y, sw);  sb = fmaf(q0.w, f0.y, sb);
                sw = fmaf(q1.x, f0.z, sw);  sb = fmaf(q1.y, f0.z, sb);
                sw = fmaf(q1.z, f0.w, sw);  sb = fmaf(q1.w, f0.w, sb);
                sw = fmaf(q2.x, f1.x, sw);  sb = fmaf(q2.y, f1.x, sb);
                sw = fmaf(q2.z, f1.y, sw);  sb = fmaf(q2.w, f1.y, sb);
                sw = fmaf(q3.x, f1.z, sw);  sb = fmaf(q3.y, f1.z, sb);
                sw = fmaf(q3.z, f1.w, sw);  sb = fmaf(q3.w, f1.w, sb);
                sw = fmaf(q4.x, f2.x, sw);  sb = fmaf(q4.y, f2.x, sb);
                sw = fmaf(q4.z, f2.y, sw);  sb = fmaf(q4.w, f2.y, sb);
                sw = fmaf(q5.x, f2.z, sw);  sb = fmaf(q5.y, f2.z, sb);
                sw = fmaf(q5.z, f2.w, sw);  sb = fmaf(q5.w, f2.w, sb);
                sw = fmaf(q6.x, f3.x, sw);  sb = fmaf(q6.y, f3.x, sb);
                sw = fmaf(q6.z, f3.y, sw);  sb = fmaf(q6.w, f3.y, sb);
                sw = fmaf(q7.x, f3.z, sw);  sb = fmaf(q7.y, f3.z, sb);
                sw = fmaf(q7.z, f3.w, sw);  sb = fmaf(q7.w, f3.w, sb);
                union { __half2 h; unsigned int u; } pk;
                pk.h = __halves2half2(__float2half(sw), __float2half(sb));
                op[(size_t)zb * (SEGS * 256)] = pk.u;
            }
        }
    }

    grid.sync();

    // ---------------- phase C ----------------
    {
        int wv   = tid >> 6;
        int lane = tid & 63;
        bool l0 = lane < 16;
        int  u = 0, part = 0;
        if (!l0) { int lu = lane - 16; u = lu / 3; part = lu - u * 3; }
        float zft = l0 ? 1.4142135623730951f : 2.0f;
        float w1v = W1[lane], b1v = b1[lane];
        float thrv = (w1v != 0.0f) ? (-b1v / w1v) : __builtin_inff();

        const float is30 = 0.18257418583505536f;
        const float is10 = 0.31622776601683794f;
        const float c1sh = 0.4886025119029199f;
        const float c21 = 1.0925484305920792f, c22 = 0.31539156525252005f, c23 = 0.5462742152960396f;

        for (int it4 = 0; it4 < 4; ++it4) {
            int bt = it4 * 640 + bid;        // bt mod 8 == bid mod 8: XCD slice kept
            int gw   = bt * 4 + wv;
            int chunk = gw & (CW - 1);
            int za    = gw >> 5;
            int z     = za / NA;

            int b0 = chunk * PPW;
            float rr[PPW], nxa[PPW], nya[PPW], nza[PPW], zfa[PPW];
            unsigned int rowo[PPW];
            #pragma unroll
            for (int it = 0; it < PPW; ++it) {
                const float* g = geom + ((size_t)za * NB + b0 + it) * 3;
                float gx = g[0], gy = g[1], gz = g[2];
                float r = sqrtf(gx * gx + gy * gy + gz * gz);
                bool zr = (r == 0.0f);
                float inv = zr ? 1.0f : (1.0f / r);
                nxa[it] = gx * inv; nya[it] = gy * inv; nza[it] = gz * inv;
                rr[it] = r;
                zfa[it] = zr ? zft : 1.0f;
                unsigned long long bm = __ballot(thrv < r);
                int s = __popcll(bm);
                rowo[it] = ((unsigned)(z * NB + b0 + it) * SEGS + (unsigned)s) * 256u
                         + (unsigned)(lane * 4);
            }

            float acc0 = 0.0f, acc1 = 0.0f, acc2 = 0.0f;
            uint4 tb[2];
            tb[0] = *(const uint4*)(PC + rowo[0]);

            #pragma unroll
            for (int it = 0; it < PPW; ++it) {
                if (it + 1 < PPW) tb[(it + 1) & 1] = *(const uint4*)(PC + rowo[it + 1]);
                uint4 tt = tb[it & 1];
                float r = rr[it];
                float T0 = rcomb(tt.x, r);
                float T1 = rcomb(tt.y, r);
                float T2 = rcomb(tt.z, r);
                float T3 = rcomb(tt.w, r);

                float nx = nxa[it], ny = nya[it], nz = nza[it];
                float Y1_0 = c1sh * ny, Y1_1 = c1sh * nz, Y1_2 = c1sh * nx;
                float zf = zfa[it];

                if (l0) {
                    float sl0 = T0;
                    sl0 = fmaf(Y1_0, T1, sl0);
                    sl0 = fmaf(Y1_1, T2, sl0);
                    sl0 = fmaf(Y1_2, T3, sl0);
                    acc0 = fmaf(sl0, zf, acc0);
                } else if (part == 0) {
                    float px = fmaf(Y1_0, T0, T1);
                    float py = fmaf(Y1_1, T0, T2);
                    float pz = fmaf(Y1_2, T0, T3);
                    acc0 = fmaf(px, zf, acc0);
                    acc1 = fmaf(py, zf, acc1);
                    acc2 = fmaf(pz, zf, acc2);
                } else if (part == 1) {
                    float px = fmaf(Y1_2, T1, -Y1_1 * T2);
                    float py = fmaf(Y1_0, T2, -Y1_2 * T0);
                    float pz = fmaf(Y1_1, T0, -Y1_0 * T1);
                    acc0 = fmaf(px, zf, acc0);
                    acc1 = fmaf(py, zf, acc1);
                    acc2 = fmaf(pz, zf, acc2);
                } else {
                    float Y2_0 = c21 * nx * ny;
                    float Y2_1 = c21 * ny * nz;
                    float Y2_2 = c22 * fmaf(3.0f, nz * nz, -1.0f);
                    float Y2_3 = c21 * nx * nz;
                    float Y2_4 = c23 * (nx * nx - ny * ny);
                    float za_ = is10 * Y2_0, zb_ = is10 * Y2_1, zc_ = is10 * Y2_3;
                    float zd_ = is30 * Y2_2, ze_ = is10 * Y2_4;
                    float px = fmaf(-(zd_ + ze_), T0, fmaf(zb_, T1, za_ * T2));
                    float py = fmaf(zb_, T0, fmaf(2.0f * zd_, T1, zc_ * T2));
                    float pz = fmaf(za_, T0, fmaf(zc_, T1, (ze_ - zd_) * T2));
                    acc0 = fmaf(px, zf, acc0);
                    acc1 = fmaf(py, zf, acc1);
                    acc2 = fmaf(pz, zf, acc2);
                }
            }

            float ax = acc0 + __shfl_down(acc0, 1) + __shfl_down(acc0, 2);
            float ay = acc1 + __shfl_down(acc1, 1) + __shfl_down(acc1, 2);
            float az = acc2 + __shfl_down(acc2, 1) + __shfl_down(acc2, 2);
            if (l0) {
                sAcc[wv][lane] = acc0;
            } else if (part == 0) {
                int ob = 16 + u * 3;
                sAcc[wv][ob]     = ax;
                sAcc[wv][ob + 1] = ay;
                sAcc[wv][ob + 2] = az;
            }
            __syncthreads();
            if (tid < 64) {
                float sum = sAcc[0][tid] + sAcc[1][tid] + sAcc[2][tid] + sAcc[3][tid];
                sum *= mask[za];
                atomicAdd(&out[(size_t)za * 64 + tid], sum);
            }
            __syncthreads();                 // sAcc reused next iteration
        }
    }
}

// ===================== fallback: proven round-5 3-dispatch path =====================
__global__ __launch_bounds__(256) void k_sw(const float* __restrict__ W1,
                                            const float* __restrict__ b1,
                                            const float* __restrict__ W2,
                                            const float* __restrict__ b2,
                                            float* __restrict__ ws,
                                            float* __restrict__ out) {
    int bid = blockIdx.x, tid = threadIdx.x;
    if (bid >= 256) {
        out[(bid - 256) * 256 + tid] = 0.0f;
        return;
    }
    int t = bid;
    __shared__ float  tvS[64];
    __shared__ float4 chS[64];
    __shared__ int    rkS[64];
    __shared__ int    ordS[64];
    __shared__ float  dwS[64], dbS[64], b2S[16];
    __shared__ float  W2t[16][65];

    if (tid < 64) {
        float w = W1[tid], bb = b1[tid];
        tvS[tid] = (w != 0.0f) ? (-bb / w) : __builtin_inff();
    }
    __syncthreads();
    if (tid < 64) {
        float mine = tvS[tid];
        int rank = 0;
        for (int j2 = 0; j2 < 64; ++j2) {
            float o = tvS[j2];
            rank += (o < mine || (o == mine && j2 < tid)) ? 1 : 0;
        }
        float w = W1[tid], bb = b1[tid];
        chS[tid] = make_float4((w > 0.0f) ? w : 0.0f,
                               (w < 0.0f) ? w : 0.0f,
                               (w > 0.0f) ? bb : 0.0f,
                               (w < 0.0f) ? bb : ((w == 0.0f && bb > 0.0f) ? bb : 0.0f));
        rkS[tid] = rank;
        ordS[rank] = tid;
        dwS[rank]  = fabsf(w);
        dbS[rank]  = (w > 0.0f) ? bb : ((w < 0.0f) ? -bb : 0.0f);
        if (t == 0) dg_thr[tid] = mine;
    }
    int pbase, pstr, comp; float scl;
    slot_map(t, pbase, pstr, comp, scl);
    (void)comp;
    int cs = tid >> 2, vq = tid & 3;
    #pragma unroll
    for (int i = 0; i < 4; ++i) {
        int v = vq * 4 + i;
        W2t[v][cs] = scl * W2[(size_t)cs * NPATH + pbase + v * pstr];
    }
    if (tid < 16) b2S[tid] = scl * b2[pbase + tid * pstr];
    __syncthreads();

    int v = tid & 15, sq = tid >> 4;
    int s0 = sq * 4;
    float sw = 0.0f, sb = 0.0f;
    #pragma unroll 8
    for (int cc = 0; cc < 64; ++cc) {
        float  w2 = W2t[v][cc];
        float4 ch = chS[cc];
        bool sel = rkS[cc] < s0;
        sw = fmaf(sel ? ch.x : ch.y, w2, sw);
        sb = fmaf(sel ? ch.z : ch.w, w2, sb);
    }
    sb += b2S[v];
    int tg = t >> 4, tl = t & 15, jj = v >> 1, half = v & 1;
    float2* swb = (float2*)(ws + SWB_OFF);
    int ns = (sq == 15) ? 5 : 4;
    for (int i = 0; i < ns; ++i) {
        int s = s0 + i, k = s >> 4, sg = s & 15;
        int flat4 = (((tg * 5 + k) * 8 + jj) * 16 + sg) * 16 + tl;
        swb[flat4 * 2 + half] = make_float2(sw, sb);
        if (i + 1 < ns) {
            float w2s = W2t[v][ordS[s]];
            sw = fmaf(dwS[s], w2s, sw);
            sb = fmaf(dbS[s], w2s, sb);
        }
    }
}

__global__ __launch_bounds__(256) void k_pc3(const float* __restrict__ feat,
                                             const float* __restrict__ ws,
                                             unsigned int* __restrict__ PC) {
    int tg = blockIdx.x & 15, zt = blockIdx.x >> 4;
    int zb0 = zt * 10;
    __shared__ __align__(16) float fS[10][64];
    #pragma unroll
    for (int i = 0; i < 3; ++i) {
        int idx = threadIdx.x + i * 256;
        if (idx < 640) {
            int row = idx >> 6, fi = idx & 63;
            float val = feat[(size_t)(zb0 + row) * 64 + fi];
            int dest;
            if (fi < 16) dest = fi;
            else { int q = (fi - 16) / 3, c3 = (fi - 16) - 3 * q; dest = (c3 + 1) * 16 + q; }
            fS[row][dest] = val;
        }
    }
    __syncthreads();
    int tl = threadIdx.x & 15, sgrp = threadIdx.x >> 4;
    int T = tg * 16 + tl;
    int pbase, pstr, comp; float scl;
    slot_map(T, pbase, pstr, comp, scl);
    (void)pbase; (void)pstr; (void)scl;
    const float* fb = &fS[0][(comp + 1) * 16];
    const float4* swb = (const float4*)(ws + SWB_OFF);
    for (int k = 0; k < 5; ++k) {
        int s = k * 16 + sgrp;
        if (s >= SEGS) break;
        int base4 = (((tg * 5 + k) * 8) * 16 + sgrp) * 16 + tl;
        float4 q0 = swb[base4];
        float4 q1 = swb[base4 + 256], q2 = swb[base4 + 512], q3 = swb[base4 + 768];
        float4 q4 = swb[base4 + 1024], q5 = swb[base4 + 1280];
        float4 q6 = swb[base4 + 1536], q7 = swb[base4 + 1792];
        unsigned int* op = PC + (size_t)zb0 * (SEGS * 256) + (size_t)s * 256 + T;
        #pragma unroll 2
        for (int zb = 0; zb < 10; ++zb) {
            const float4* fp = (const float4*)(fb + zb * 64);
            float4 f0 = fp[0], f1 = fp[1], f2 = fp[2], f3 = fp[3];
            float sw = q0.x * f0.x,          sb = q0.y * f0.x;
            sw = fmaf(q0.z, f0.y, sw);  sb = fmaf(q0.w, f0.y, sb);
            sw = fmaf(q1.x, f0.z, sw);  sb = fmaf(q1.y, f0.z, sb);
            sw = fmaf(q1.z, f0.w, sw);  sb = fmaf(q1.w, f0.w, sb);
            sw = fmaf(q2.x, f1.x, sw);  sb = fmaf(q2.y, f1.x, sb);
            sw = fmaf(q2.z, f1.y, sw);  sb = fmaf(q2.w, f1.y, sb);
            sw = fmaf(q3.x, f1.z, sw);  sb = fmaf(q3.y, f1.z, sb);
            sw = fmaf(q3.z, f1.w, sw);  sb = fmaf(q3.w, f1.w, sb);
            sw = fmaf(q4.x, f2.x, sw);  sb = fmaf(q4.y, f2.x, sb);
            sw = fmaf(q4.z, f2.y, sw);  sb = fmaf(q4.w, f2.y, sb);
            sw = fmaf(q5.x, f2.z, sw);  sb = fmaf(q5.y, f2.z, sb);
            sw = fmaf(q5.z, f2.w, sw);  sb = fmaf(q5.w, f2.w, sb);
            sw = fmaf(q6.x, f3.x, sw);  sb = fmaf(q6.y, f3.x, sb);
            sw = fmaf(q6.z, f3.y, sw);  sb = fmaf(q6.w, f3.y, sb);
            sw = fmaf(q7.x, f3.z, sw);  sb = fmaf(q7.y, f3.z, sb);
            sw = fmaf(q7.z, f3.w, sw);  sb = fmaf(q7.w, f3.w, sb);
            union { __half2 h; unsigned int u; } pk;
            pk.h = __halves2half2(__float2half(sw), __float2half(sb));
            op[(size_t)zb * (SEGS * 256)] = pk.u;
        }
    }
}

__global__ __launch_bounds__(256, 4) void k_main(const float* __restrict__ geom,
                                                 const float* __restrict__ mask,
                                                 const unsigned int* __restrict__ PC,
                                                 float* __restrict__ out) {
    int wv   = threadIdx.x >> 6;
    int lane = threadIdx.x & 63;
    int gw   = blockIdx.x * 4 + wv;
    int chunk = gw & (CW - 1);
    int za    = gw >> 5;
    int z     = za / NA;
    __shared__ float sAcc[4][64];
    bool l0 = lane < 16;
    int  u = 0, part = 0;
    if (!l0) { int lu = lane - 16; u = lu / 3; part = lu - u * 3; }
    float zft = l0 ? 1.4142135623730951f : 2.0f;
    float thrv = dg_thr[lane];
    const float is30 = 0.18257418583505536f;
    const float is10 = 0.31622776601683794f;
    const float c1sh = 0.4886025119029199f;
    const float c21 = 1.0925484305920792f, c22 = 0.31539156525252005f, c23 = 0.5462742152960396f;
    int b0 = chunk * PPW;
    float rr[PPW], nxa[PPW], nya[PPW], nza[PPW], zfa[PPW];
    unsigned int rowo[PPW];
    #pragma unroll
    for (int it = 0; it < PPW; ++it) {
        const float* g = geom + ((size_t)za * NB + b0 + it) * 3;
        float gx = g[0], gy = g[1], gz = g[2];
        float r = sqrtf(gx * gx + gy * gy + gz * gz);
        bool zr = (r == 0.0f);
        float inv = zr ? 1.0f : (1.0f / r);
        nxa[it] = gx * inv; nya[it] = gy * inv; nza[it] = gz * inv;
        rr[it] = r;
        zfa[it] = zr ? zft : 1.0f;
        unsigned long long bm = __ballot(thrv < r);
        int s = __popcll(bm);
        rowo[it] = ((unsigned)(z * NB + b0 + it) * SEGS + (unsigned)s) * 256u
                 + (unsigned)(lane * 4);
    }
    float acc0 = 0.0f, acc1 = 0.0f, acc2 = 0.0f;
    uint4 tb[2];
    tb[0] = *(const uint4*)(PC + rowo[0]);
    #pragma unroll
    for (int it = 0; it < PPW; ++it) {
        if (it + 1 < PPW) tb[(it + 1) & 1] = *(const uint4*)(PC + rowo[it + 1]);
        uint4 tt = tb[it & 1];
        float r = rr[it];
        float T0 = rcomb(tt.x, r);
        float T1 = rcomb(tt.y, r);
        float T2 = rcomb(tt.z, r);
        float T3 = rcomb(tt.w, r);
        float nx = nxa[it], ny = nya[it], nz = nza[it];
        float Y1_0 = c1sh * ny, Y1_1 = c1sh * nz, Y1_2 = c1sh * nx;
        float zf = zfa[it];
        if (l0) {
            float sl0 = T0;
            sl0 = fmaf(Y1_0, T1, sl0);
            sl0 = fmaf(Y1_1, T2, sl0);
            sl0 = fmaf(Y1_2, T3, sl0);
            acc0 = fmaf(sl0, zf, acc0);
        } else if (part == 0) {
            float px = fmaf(Y1_0, T0, T1);
            float py = fmaf(Y1_1, T0, T2);
            float pz = fmaf(Y1_2, T0, T3);
            acc0 = fmaf(px, zf, acc0);
            acc1 = fmaf(py, zf, acc1);
            acc2 = fmaf(pz, zf, acc2);
        } else if (part == 1) {
            float px = fmaf(Y1_2, T1, -Y1_1 * T2);
            float py = fmaf(Y1_0, T2, -Y1_2 * T0);
            float pz = fmaf(Y1_1, T0, -Y1_0 * T1);
            acc0 = fmaf(px, zf, acc0);
            acc1 = fmaf(py, zf, acc1);
            acc2 = fmaf(pz, zf, acc2);
        } else {
            float Y2_0 = c21 * nx * ny;
            float Y2_1 = c21 * ny * nz;
            float Y2_2 = c22 * fmaf(3.0f, nz * nz, -1.0f);
            float Y2_3 = c21 * nx * nz;
            float Y2_4 = c23 * (nx * nx - ny * ny);
            float za_ = is10 * Y2_0, zb_ = is10 * Y2_1, zc_ = is10 * Y2_3;
            float zd_ = is30 * Y2_2, ze_ = is10 * Y2_4;
            float px = fmaf(-(zd_ + ze_), T0, fmaf(zb_, T1, za_ * T2));
            float py = fmaf(zb_, T0, fmaf(2.0f * zd_, T1, zc_ * T2));
            float pz = fmaf(za_, T0, fmaf(zc_, T1, (ze_ - zd_) * T2));
            acc0 = fmaf(px, zf, acc0);
            acc1 = fmaf(py, zf, acc1);
            acc2 = fmaf(pz, zf, acc2);
        }
    }
    float ax = acc0 + __shfl_down(acc0, 1) + __shfl_down(acc0, 2);
    float ay = acc1 + __shfl_down(acc1, 1) + __shfl_down(acc1, 2);
    float az = acc2 + __shfl_down(acc2, 1) + __shfl_down(acc2, 2);
    if (l0) {
        sAcc[wv][lane] = acc0;
    } else if (part == 0) {
        int ob = 16 + u * 3;
        sAcc[wv][ob]     = ax;
        sAcc[wv][ob + 1] = ay;
        sAcc[wv][ob + 2] = az;
    }
    __syncthreads();
    if (threadIdx.x < 64) {
        float sum = sAcc[0][threadIdx.x] + sAcc[1][threadIdx.x]
                  + sAcc[2][threadIdx.x] + sAcc[3][threadIdx.x];
        sum *= mask[za];
        atomicAdd(&out[(size_t)za * 64 + threadIdx.x], sum);
    }
}

extern "C" void kernel_launch(void* const* d_in, const int* in_sizes, int n_in,
                              void* d_out, int out_size, void* d_ws, size_t ws_size,
                              hipStream_t stream) {
    (void)in_sizes; (void)n_in; (void)ws_size; (void)out_size;
    const float* feat = (const float*)d_in[0];
    const float* geom = (const float*)d_in[1];
    const float* mask = (const float*)d_in[2];
    const float* W1   = (const float*)d_in[3];
    const float* b1   = (const float*)d_in[4];
    const float* W2   = (const float*)d_in[5];
    const float* b2   = (const float*)d_in[6];
    float* out = (float*)d_out;
    float* ws  = (float*)d_ws;                 // PC (21.3MB) | SWB2 (2.6MB)
    unsigned int* PC = (unsigned int*)d_ws;

    void* args[] = {(void*)&feat, (void*)&geom, (void*)&mask, (void*)&W1,
                    (void*)&b1, (void*)&W2, (void*)&b2, (void*)&ws, (void*)&out};
    hipError_t e = hipLaunchCooperativeKernel((const void*)k_all, dim3(640),
                                              dim3(256), args, 0, stream);
    if (e != hipSuccess) {
        // fallback: proven 3-dispatch path (round-5 behavior)
        k_sw  <<<336, 256, 0, stream>>>(W1, b1, W2, b2, ws, out);
        k_pc3 <<<512, 256, 0, stream>>>(feat, ws, PC);
        k_main<<<2 * NA * CW / 4, 256, 0, stream>>>(geom, mask, PC, out);
    }
}

// Round 7
// 100.767 us; speedup vs baseline: 2.5852x; 2.5852x over previous
//
#include <hip/hip_runtime.h>
#include <hip/hip_fp16.h>
#include <math.h>

#define NPATH 1536
#define SEGS  65        // 0..64 active-channel counts
#define NB    160
#define NA    160

// d_ws layout:
//   [0, 21.3MB)  PC[zb][seg][256 u32]  — packed {fp16 slope | fp16 icpt}
//   [21.3MB, +2.6MB) SWB2 — feature-independent per-slot segment table:
//     float4 index (T = tg*16+tl, s = k*16+sgrp, j = v-pair):
//       flat4 = (((tg*5 + k)*8 + j)*16 + sgrp)*16 + tl
//     float4 = {sw(v=2j), sb(2j), sw(2j+1), sb(2j+1)}  (k=4: only sgrp=0 used)
// slot t = lane*4 + j (k_main reads uint4 per lane):
//   lane  0..15 (l0 task u=lane): j0 = A(u)->T0 ; j1..3 = B(u,xyz)->T1c
//   lane 16..63 (l1 task u=(lane-16)/3, part=(lane-16)%3):
//     part0: j0 = C(u)->T0 ; j1..3 = D(u,xyz)->T1c
//     part1: j0..2 = E(u,xyz)->T2c ; j3 pad
//     part2: j0..2 = F(u,xyz)->T3c ; j3 pad
#define PC_U32S   (320 * SEGS * 256)            // 5,324,800 u32
#define SWB_OFF   PC_U32S                        // float offset into ws

#define SCL_A 0.17677669529663687f
#define SCL_B 0.6266570686577502f
#define SCL_C 0.2558286876965162f
#define SCL_D 0.125f
#define SCL_E 0.3133285343288751f
#define SCL_F 0.7674950309598664f

// slot t -> (path base, path stride, feature component, folded scale).
// comp == -1 -> feature f[v]; else f[16 + 3v + comp]. Pad slots: scl = 0.
static __device__ __forceinline__ void slot_map(int t, int& pbase, int& pstr,
                                                int& comp, float& scl) {
    int lane4 = t >> 2, j = t & 3;
    pbase = 0; pstr = 1; comp = -1; scl = 0.0f;
    if (lane4 < 16) {
        if (j == 0) { pbase = lane4 * 16;       scl = SCL_A; }
        else        { pbase = 256 + lane4 * 16; comp = j - 1; scl = SCL_B; }
    } else {
        int lu = lane4 - 16, u = lu / 3, part = lu - u * 3;
        if (part == 0) {
            if (j == 0) { pbase = 512 + u * 16;                       scl = SCL_C; }
            else        { pbase = 768 + u * 48; pstr = 3; comp = j - 1; scl = SCL_D; }
        } else if (part == 1) {
            if (j < 3)  { pbase = 768 + u * 48 + 1; pstr = 3; comp = j; scl = SCL_E; }
        } else {
            if (j < 3)  { pbase = 768 + u * 48 + 2; pstr = 3; comp = j; scl = SCL_F; }
        }
    }
}

static __device__ __forceinline__ float rcomb(unsigned int v, float r) {
    union { unsigned int u; __half2 h; } cv; cv.u = v;
    return fmaf(r, __low2float(cv.h), __high2float(cv.h));
}

// blocks 0..255: one per slot t (SWB2 build, threshold-prefix over channels).
// blocks 256..335: zero d_out (80 x 256 = 20480 floats).
__global__ __launch_bounds__(256) void k_sw(const float* __restrict__ W1,
                                            const float* __restrict__ b1,
                                            const float* __restrict__ W2,
                                            const float* __restrict__ b2,
                                            float* __restrict__ ws,
                                            float* __restrict__ out) {
    int bid = blockIdx.x, tid = threadIdx.x;
    if (bid >= 256) {
        out[(bid - 256) * 256 + tid] = 0.0f;
        return;
    }
    int t = bid;
    __shared__ float  tvS[64];
    __shared__ float4 chS[64];              // {wPos, wNeg, bSel, bUnsel}
    __shared__ int    rkS[64];
    __shared__ int    ordS[64];
    __shared__ float  dwS[64], dbS[64], b2S[16];
    __shared__ float  W2t[16][65];          // pad 65

    if (tid < 64) {
        float w = W1[tid], bb = b1[tid];
        tvS[tid] = (w != 0.0f) ? (-bb / w) : __builtin_inff();
    }
    __syncthreads();
    if (tid < 64) {
        float mine = tvS[tid];
        int rank = 0;
        for (int j2 = 0; j2 < 64; ++j2) {
            float o = tvS[j2];
            rank += (o < mine || (o == mine && j2 < tid)) ? 1 : 0;
        }
        float w = W1[tid], bb = b1[tid];
        // sel (= rank < s): threshold-passed set. w>0 active iff sel;
        // w<0 active iff !sel; w==0 active iff b>0 (always !sel).
        chS[tid] = make_float4((w > 0.0f) ? w : 0.0f,
                               (w < 0.0f) ? w : 0.0f,
                               (w > 0.0f) ? bb : 0.0f,
                               (w < 0.0f) ? bb : ((w == 0.0f && bb > 0.0f) ? bb : 0.0f));
        rkS[tid] = rank;
        // step s -> s+1 flips the channel with rank s: w>0 adds, w<0 removes
        ordS[rank] = tid;
        dwS[rank]  = fabsf(w);
        dbS[rank]  = (w > 0.0f) ? bb : ((w < 0.0f) ? -bb : 0.0f);
    }
    int pbase, pstr, comp; float scl;
    slot_map(t, pbase, pstr, comp, scl);
    (void)comp;
    int cs = tid >> 2, vq = tid & 3;        // 16 c-rows per wave-instr
    #pragma unroll
    for (int i = 0; i < 4; ++i) {
        int v = vq * 4 + i;
        W2t[v][cs] = scl * W2[(size_t)cs * NPATH + pbase + v * pstr];
    }
    if (tid < 16) b2S[tid] = scl * b2[pbase + tid * pstr];
    __syncthreads();

    int v = tid & 15, sq = tid >> 4;        // 16 v x 16 s-quads
    int s0 = sq * 4;
    float sw = 0.0f, sb = 0.0f;
    #pragma unroll 8
    for (int cc = 0; cc < 64; ++cc) {
        float  w2 = W2t[v][cc];
        float4 ch = chS[cc];                // broadcast
        bool sel = rkS[cc] < s0;
        sw = fmaf(sel ? ch.x : ch.y, w2, sw);
        sb = fmaf(sel ? ch.z : ch.w, w2, sb);
    }
    sb += b2S[v];

    int tg = t >> 4, tl = t & 15, jj = v >> 1, half = v & 1;
    float2* swb = (float2*)(ws + SWB_OFF);
    int ns = (sq == 15) ? 5 : 4;            // sq 15 also writes s=64
    for (int i = 0; i < ns; ++i) {
        int s = s0 + i, k = s >> 4, sg = s & 15;
        int flat4 = (((tg * 5 + k) * 8 + jj) * 16 + sg) * 16 + tl;
        swb[flat4 * 2 + half] = make_float2(sw, sb);
        if (i + 1 < ns) {
            float w2s = W2t[v][ordS[s]];
            sw = fmaf(dwS[s], w2s, sw);
            sb = fmaf(dbS[s], w2s, sb);
        }
    }
}

// Tiny batched GEMM: PC[zb][s][T] = pack(sum_v f*SW, sum_v f*SB).
// grid = 16 t-groups x 32 zb-tiles (tile=10). SWB2 layout makes each of the
// 8 q-loads a fully-contiguous 1KB wave transaction.
__global__ __launch_bounds__(256) void k_pc3(const float* __restrict__ feat,
                                             const float* __restrict__ ws,
                                             unsigned int* __restrict__ PC) {
    int tg = blockIdx.x & 15, zt = blockIdx.x >> 4;
    int zb0 = zt * 10;
    __shared__ __align__(16) float fS[10][64];   // [zb][ct*16 + v]
    #pragma unroll
    for (int i = 0; i < 3; ++i) {
        int idx = threadIdx.x + i * 256;
        if (idx < 640) {
            int row = idx >> 6, fi = idx & 63;
            float val = feat[(size_t)(zb0 + row) * 64 + fi];
            int dest;
            if (fi < 16) dest = fi;
            else { int q = (fi - 16) / 3, c3 = (fi - 16) - 3 * q; dest = (c3 + 1) * 16 + q; }
            fS[row][dest] = val;
        }
    }
    __syncthreads();
    int tl = threadIdx.x & 15, sgrp = threadIdx.x >> 4;
    int T = tg * 16 + tl;
    int pbase, pstr, comp; float scl;
    slot_map(T, pbase, pstr, comp, scl);
    (void)pbase; (void)pstr; (void)scl;
    const float* fb = &fS[0][(comp + 1) * 16];
    const float4* swb = (const float4*)(ws + SWB_OFF);
    for (int k = 0; k < 5; ++k) {
        int s = k * 16 + sgrp;
        if (s >= SEGS) break;                // only k=4, sgrp>0 exits
        int base4 = (((tg * 5 + k) * 8) * 16 + sgrp) * 16 + tl;
        float4 q0 = swb[base4];
        float4 q1 = swb[base4 + 256], q2 = swb[base4 + 512], q3 = swb[base4 + 768];
        float4 q4 = swb[base4 + 1024], q5 = swb[base4 + 1280];
        float4 q6 = swb[base4 + 1536], q7 = swb[base4 + 1792];
        unsigned int* op = PC + (size_t)zb0 * (SEGS * 256) + (size_t)s * 256 + T;
        #pragma unroll 2
        for (int zb = 0; zb < 10; ++zb) {
            const float4* fp = (const float4*)(fb + zb * 64);
            float4 f0 = fp[0], f1 = fp[1], f2 = fp[2], f3 = fp[3];
            float sw = q0.x * f0.x,          sb = q0.y * f0.x;
            sw = fmaf(q0.z, f0.y, sw);  sb = fmaf(q0.w, f0.y, sb);
            sw = fmaf(q1.x, f0.z, sw);  sb = fmaf(q1.y, f0.z, sb);
            sw = fmaf(q1.z, f0.w, sw);  sb = fmaf(q1.w, f0.w, sb);
            sw = fmaf(q2.x, f1.x, sw);  sb = fmaf(q2.y, f1.x, sb);
            sw = fmaf(q2.z, f1.y, sw);  sb = fmaf(q2.w, f1.y, sb);
            sw = fmaf(q3.x, f1.z, sw);  sb = fmaf(q3.y, f1.z, sb);
            sw = fmaf(q3.z, f1.w, sw);  sb = fmaf(q3.w, f1.w, sb);
            sw = fmaf(q4.x, f2.x, sw);  sb = fmaf(q4.y, f2.x, sb);
            sw = fmaf(q4.z, f2.y, sw);  sb = fmaf(q4.w, f2.y, sb);
            sw = fmaf(q5.x, f2.z, sw);  sb = fmaf(q5.y, f2.z, sb);
            sw = fmaf(q5.z, f2.w, sw);  sb = fmaf(q5.w, f2.w, sb);
            sw = fmaf(q6.x, f3.x, sw);  sb = fmaf(q6.y, f3.x, sb);
            sw = fmaf(q6.z, f3.y, sw);  sb = fmaf(q6.w, f3.y, sb);
            sw = fmaf(q7.x, f3.z, sw);  sb = fmaf(q7.y, f3.z, sb);
            sw = fmaf(q7.z, f3.w, sw);  sb = fmaf(q7.w, f3.w, sb);
            union { __half2 h; unsigned int u; } pk;
            pk.h = __halves2half2(__float2half(sw), __float2half(sb));
            op[(size_t)zb * (SEGS * 256)] = pk.u;
        }
    }
}

// block = (za, half): 640 blocks x 256 threads. Each wave owns 20 consecutive
// b (b = half*80 + wv*20 + q) with a 2-stage pipeline: geometry/ballot for
// q+1 + PC-row issue overlap the consumption of row q. 2 atomic writers per
// output (was 8). thrv computed locally (no dg_thr dependency).
__global__ __launch_bounds__(256, 4) void k_main(const float* __restrict__ geom,
                                                 const float* __restrict__ mask,
                                                 const float* __restrict__ W1,
                                                 const float* __restrict__ b1,
                                                 const unsigned int* __restrict__ PC,
                                                 float* __restrict__ out) {
    int wv   = threadIdx.x >> 6;
    int lane = threadIdx.x & 63;
    int bid  = blockIdx.x;
    int za   = bid >> 1, half = bid & 1;
    int z    = za / NA;

    __shared__ float sAcc[4][64];

    bool l0 = lane < 16;
    int  u = 0, part = 0;
    if (!l0) { int lu = lane - 16; u = lu / 3; part = lu - u * 3; }
    float zft = l0 ? 1.4142135623730951f : 2.0f;   // zero-radius norm ratio
    float w1v = W1[lane], b1v = b1[lane];
    float thrv = (w1v != 0.0f) ? (-b1v / w1v) : __builtin_inff();

    const float is30 = 0.18257418583505536f;  // 1/sqrt(30)
    const float is10 = 0.31622776601683794f;  // 1/sqrt(10)
    const float c1sh = 0.4886025119029199f;
    const float c21 = 1.0925484305920792f, c22 = 0.31539156525252005f, c23 = 0.5462742152960396f;

    int b0 = half * 80 + wv * 20;
    const float* gbase = geom + ((size_t)za * NB + b0) * 3;
    unsigned int zbase = (unsigned)(z * NB + b0);

    float acc0 = 0.0f, acc1 = 0.0f, acc2 = 0.0f;

    // ---- stage 0 ----
    float r_c, nx_c, ny_c, nz_c, zf_c;
    {
        float gx = gbase[0], gy = gbase[1], gz = gbase[2];
        float r = sqrtf(gx * gx + gy * gy + gz * gz);
        bool zr = (r == 0.0f);
        float inv = zr ? 1.0f : (1.0f / r);
        nx_c = gx * inv; ny_c = gy * inv; nz_c = gz * inv;
        r_c = r; zf_c = zr ? zft : 1.0f;
    }
    unsigned long long bm0 = __ballot(thrv < r_c);
    unsigned int ro_c = (zbase * SEGS + (unsigned)__popcll(bm0)) * 256u
                      + (unsigned)(lane * 4);
    uint4 tb0 = *(const uint4*)(PC + ro_c);

    for (int q = 0; q < 20; ++q) {
        // ---- issue stage q+1 while tb0 is in flight / being consumed ----
        float r_n = 0.0f, nx_n = 0.0f, ny_n = 0.0f, nz_n = 0.0f, zf_n = 0.0f;
        uint4 tb1 = tb0;
        if (q + 1 < 20) {
            const float* g = gbase + (q + 1) * 3;
            float gx = g[0], gy = g[1], gz = g[2];
            float r = sqrtf(gx * gx + gy * gy + gz * gz);
            bool zr = (r == 0.0f);
            float inv = zr ? 1.0f : (1.0f / r);
            nx_n = gx * inv; ny_n = gy * inv; nz_n = gz * inv;
            r_n = r; zf_n = zr ? zft : 1.0f;
            unsigned long long bm = __ballot(thrv < r);
            unsigned int ro_n = ((zbase + (unsigned)(q + 1)) * SEGS
                                 + (unsigned)__popcll(bm)) * 256u
                              + (unsigned)(lane * 4);
            tb1 = *(const uint4*)(PC + ro_n);
        }

        // ---- consume stage q ----
        uint4 tt = tb0;
        float r = r_c;
        float T0 = rcomb(tt.x, r);
        float T1 = rcomb(tt.y, r);
        float T2 = rcomb(tt.z, r);
        float T3 = rcomb(tt.w, r);

        float nx = nx_c, ny = ny_c, nz = nz_c;
        float Y1_0 = c1sh * ny, Y1_1 = c1sh * nz, Y1_2 = c1sh * nx;
        float zf = zf_c;

        if (l0) {
            // out(l0,u) partial: T0 + Y1 . T1vec
            float sl0 = T0;
            sl0 = fmaf(Y1_0, T1, sl0);
            sl0 = fmaf(Y1_1, T2, sl0);
            sl0 = fmaf(Y1_2, T3, sl0);
            acc0 = fmaf(sl0, zf, acc0);
        } else if (part == 0) {
            // T0 (C) + T1vec (D) terms of s_xyz
            float px = fmaf(Y1_0, T0, T1);
            float py = fmaf(Y1_1, T0, T2);
            float pz = fmaf(Y1_2, T0, T3);
            acc0 = fmaf(px, zf, acc0);
            acc1 = fmaf(py, zf, acc1);
            acc2 = fmaf(pz, zf, acc2);
        } else if (part == 1) {
            // T2vec (E) cross terms
            float px = fmaf(Y1_2, T1, -Y1_1 * T2);
            float py = fmaf(Y1_0, T2, -Y1_2 * T0);
            float pz = fmaf(Y1_1, T0, -Y1_0 * T1);
            acc0 = fmaf(px, zf, acc0);
            acc1 = fmaf(py, zf, acc1);
            acc2 = fmaf(pz, zf, acc2);
        } else {
            // T3vec (F) l=2 terms
            float Y2_0 = c21 * nx * ny;
            float Y2_1 = c21 * ny * nz;
            float Y2_2 = c22 * fmaf(3.0f, nz * nz, -1.0f);
            float Y2_3 = c21 * nx * nz;
            float Y2_4 = c23 * (nx * nx - ny * ny);
            float za_ = is10 * Y2_0, zb_ = is10 * Y2_1, zc_ = is10 * Y2_3;
            float zd_ = is30 * Y2_2, ze_ = is10 * Y2_4;
            float px = fmaf(-(zd_ + ze_), T0, fmaf(zb_, T1, za_ * T2));
            float py = fmaf(zb_, T0, fmaf(2.0f * zd_, T1, zc_ * T2));
            float pz = fmaf(za_, T0, fmaf(zc_, T1, (ze_ - zd_) * T2));
            acc0 = fmaf(px, zf, acc0);
            acc1 = fmaf(py, zf, acc1);
            acc2 = fmaf(pz, zf, acc2);
        }

        // ---- shift pipeline ----
        r_c = r_n; nx_c = nx_n; ny_c = ny_n; nz_c = nz_n; zf_c = zf_n;
        tb0 = tb1;
    }

    // ---- combine the 3 l1 parts (lanes 16+3u+{0,1,2}) ----
    float ax = acc0 + __shfl_down(acc0, 1) + __shfl_down(acc0, 2);
    float ay = acc1 + __shfl_down(acc1, 1) + __shfl_down(acc1, 2);
    float az = acc2 + __shfl_down(acc2, 1) + __shfl_down(acc2, 2);
    if (l0) {
        sAcc[wv][lane] = acc0;
    } else if (part == 0) {
        int ob = 16 + u * 3;
        sAcc[wv][ob]     = ax;
        sAcc[wv][ob + 1] = ay;
        sAcc[wv][ob + 2] = az;
    }
    __syncthreads();
    if (threadIdx.x < 64) {
        float sum = sAcc[0][threadIdx.x] + sAcc[1][threadIdx.x]
                  + sAcc[2][threadIdx.x] + sAcc[3][threadIdx.x];
        sum *= mask[za];
        atomicAdd(&out[(size_t)za * 64 + threadIdx.x], sum);
    }
}

extern "C" void kernel_launch(void* const* d_in, const int* in_sizes, int n_in,
                              void* d_out, int out_size, void* d_ws, size_t ws_size,
                              hipStream_t stream) {
    (void)in_sizes; (void)n_in; (void)ws_size; (void)out_size;
    const float* feat = (const float*)d_in[0];
    const float* geom = (const float*)d_in[1];
    const float* mask = (const float*)d_in[2];
    const float* W1   = (const float*)d_in[3];
    const float* b1   = (const float*)d_in[4];
    const float* W2   = (const float*)d_in[5];
    const float* b2   = (const float*)d_in[6];
    float* out = (float*)d_out;
    float* ws  = (float*)d_ws;                 // PC (21.3MB) | SWB2 (2.6MB)
    unsigned int* PC = (unsigned int*)d_ws;

    k_sw  <<<336, 256, 0, stream>>>(W1, b1, W2, b2, ws, out);  // 256 table + 80 zero
    k_pc3 <<<512, 256, 0, stream>>>(feat, ws, PC);
    k_main<<<640, 256, 0, stream>>>(geom, mask, W1, b1, PC, out);
}

// Round 8
// 92.127 us; speedup vs baseline: 2.8277x; 1.0938x over previous
//
#include <hip/hip_runtime.h>
#include <hip/hip_fp16.h>
#include <math.h>

#define NPATH 1536
#define NSEG  65
#define NB    160
#define NA    160
#define CW    32   // chunks (waves) per (z,a)
#define PPW   5    // pairs per wave = NB/CW

// Piecewise-linear radial-MLP table, fp16-packed: one 16B entry holds a
// lane's 4 slots: {h2(s0,s1), h2(s2,s3), h2(i0,i1), h2(i2,i3)}; R_k(r) =
// r*s_k + i_k (computed in f32). Per-block Wigner/norm constants pre-folded.
// Per segment: 512 entries (8 KB): [0..255] l0 (v*16+u) -> slots {A,B,0,0};
// [256..511] l1 (v*16+u) -> slots {C,D,E,F}.
__device__ float  dg_thr[64];    // per-channel threshold -b1/W1 (inf if W1==0)
__device__ float4 dg_tbl4[NSEG * 512];

static __device__ __forceinline__ __half2 bc_h2(float x) {
    union { float f; __half2 h; } u; u.f = x; return u.h;
}
static __device__ __forceinline__ unsigned short h_us(__half h) {
    union { __half h; unsigned short s; } u; u.h = h; return u.s;
}

// blocks 0..389: table (one thread per (segment,path), direct masked sums —
// activity is a pure rank predicate, rank-sort recomputed per block).
// blocks 390..469: zero d_out.
__global__ __launch_bounds__(256) void k_prep(const float* __restrict__ W1,
                                              const float* __restrict__ b1,
                                              const float* __restrict__ W2,
                                              const float* __restrict__ b2,
                                              float* __restrict__ out) {
    int bid = blockIdx.x, tid = threadIdx.x;
    if (bid >= 390) {
        out[(bid - 390) * 256 + tid] = 0.0f;
        return;
    }
    int tseg = bid / 6, tcol = bid % 6;
    __shared__ float tv[64], mw[64], mb[64];
    if (tid < 64) {
        float w = W1[tid], b = b1[tid];
        tv[tid] = (w != 0.0f) ? (-b / w) : __builtin_inff();
    }
    __syncthreads();
    if (tid < 64) {
        float mine = tv[tid];
        int rank = 0;
        for (int j = 0; j < 64; ++j) {
            float o = tv[j];
            rank += (o < mine || (o == mine && j < tid)) ? 1 : 0;
        }
        float w = W1[tid], b = b1[tid];
        // active at segment s (= #thresholds < r):
        //   w>0: rank < s ; w<0: rank >= s ; w==0: b>0
        bool act = (w > 0.0f) ? (rank < tseg)
                 : (w < 0.0f) ? (rank >= tseg)
                              : (b > 0.0f);
        mw[tid] = act ? w : 0.0f;
        mb[tid] = act ? b : 0.0f;
        if (bid == 0) dg_thr[tid] = mine;
    }
    __syncthreads();

    int p = tcol * 256 + tid;
    int e, k; float scl;
    if (p < 768) {
        int u = (p >> 4) & 15, v = p & 15, vu = v * 16 + u;
        if (p < 256)      { e = vu;       k = 0; scl = 0.17677669529663687f; } // A
        else if (p < 512) { e = vu;       k = 1; scl = 0.6266570686577502f;  } // B
        else              { e = 256 + vu; k = 0; scl = 0.2558286876965162f;  } // C
    } else {
        int m = (p - 768) / 3, kk = (p - 768) % 3;
        int u = m >> 4, v = m & 15, vu = v * 16 + u;
        e = 256 + vu;
        if (kk == 0)      { k = 1; scl = 0.125f;              }  // D
        else if (kk == 1) { k = 2; scl = 0.3133285343288751f; }  // E
        else              { k = 3; scl = 0.7674950309598664f; }  // F
    }

    float A = 0.0f, B = 0.0f;
    #pragma unroll 8
    for (int c = 0; c < 64; ++c) {
        float w2 = W2[c * NPATH + p];   // coalesced across tid; W2 is L2-hot
        A = fmaf(mw[c], w2, A);
        B = fmaf(mb[c], w2, B);
    }
    float sv = scl * A;
    float iv = scl * (B + b2[p]);

    unsigned short* ub = (unsigned short*)dg_tbl4 + ((size_t)tseg * 512 + e) * 8;
    ub[k]     = h_us(__float2half(sv));   // slope slot k  (ushorts 0..3)
    ub[4 + k] = h_us(__float2half(iv));   // icpt  slot k  (ushorts 4..7)
    if (p < 256) {                        // A-thread zeroes the l0 pad slots 2,3
        ((unsigned int*)ub)[1] = 0u;      // s2,s3
        ((unsigned int*)ub)[3] = 0u;      // i2,i3
    }
}

__global__ __launch_bounds__(256, 4) void k_main(const float* __restrict__ feat,
                                                 const float* __restrict__ geom,
                                                 const float* __restrict__ mask,
                                                 float* __restrict__ out) {
    int wv   = threadIdx.x >> 6;
    int lane = threadIdx.x & 63;
    int gw   = blockIdx.x * 4 + wv;     // 4 waves of a block share za
    int chunk = gw & (CW - 1);
    int za    = gw >> 5;                // z*160 + a
    int z     = za / NA;

    __shared__ __align__(16) float sFeat[4][PPW][64]; // slot v = {f1x,f1y,f1z,f0}
    __shared__ float sAcc[4][64];

    // ---- v-split task assignment (dedup: 32 tasks x 2 v-halves) ----
    int h    = lane >> 5;          // which v-half this lane accumulates
    int l32  = lane & 31;
    bool tl0 = l32 < 16;           // task type: l0 (A/B) vs l1 (C/D/E/F)
    int  tu  = l32 & 15;           // task u
    int  e_base = (tl0 ? 0 : 256) + h * 16 + tu;   // entry idx of (v=h, u)
    float zft = tl0 ? 1.4142135623730951f : 2.0f;  // zero-radius norm ratio (task)

    // input staging address (same layout as before)
    int waddr = (lane < 16) ? (lane * 4 + 3)
                            : (((lane - 16) / 3) * 4 + ((lane - 16) % 3));

    float thrv = dg_thr[lane];

    const float is30 = 0.18257418583505536f;  // 1/sqrt(30)
    const float is10 = 0.31622776601683794f;  // 1/sqrt(10)
    const float c1sh = 0.4886025119029199f;
    const float c21 = 1.0925484305920792f, c22 = 0.31539156525252005f, c23 = 0.5462742152960396f;

    // ---- stage all PPW feature rows (wave-private LDS slot, no barrier) ----
    int b0 = chunk * PPW;
    #pragma unroll
    for (int it = 0; it < PPW; ++it) {
        float fv = feat[((size_t)(z * NB + b0 + it)) * 64 + lane];
        sFeat[wv][it][waddr] = fv;
    }

    // ---- precompute geometry/segment for all PPW pairs ----
    float rr[PPW], nxa[PPW], nya[PPW], nza[PPW], zfa[PPW];
    int rowo[PPW];
    #pragma unroll
    for (int it = 0; it < PPW; ++it) {
        const float* g = geom + ((size_t)za * NB + b0 + it) * 3;
        float gx = g[0], gy = g[1], gz = g[2];
        float r = sqrtf(gx * gx + gy * gy + gz * gz);
        bool zr = (r == 0.0f);
        float inv = zr ? 1.0f : (1.0f / r);
        nxa[it] = gx * inv; nya[it] = gy * inv; nza[it] = gz * inv;
        rr[it] = r;
        zfa[it] = zr ? zft : 1.0f;
        unsigned long long bm = __ballot(thrv < r);
        rowo[it] = __popcll(bm) * 512;
    }

    // per-task output accumulators: l0 task -> acc0; l1 task -> acc0/1/2 = s_x/y/z
    float acc0 = 0.0f, acc1 = 0.0f, acc2 = 0.0f;

    // ---- software pipeline: register double-buffer of table entries ----
    float4 tb[2][8];
    {
        const float4* __restrict__ rp0 = dg_tbl4 + rowo[0] + e_base;
        #pragma unroll
        for (int s = 0; s < 8; ++s) tb[0][s] = rp0[s * 32];
    }

    #pragma unroll
    for (int it = 0; it < PPW; ++it) {
        // issue next pair's loads before consuming this pair's buffer
        if (it + 1 < PPW) {
            const float4* __restrict__ rpn = dg_tbl4 + rowo[it + 1] + e_base;
            #pragma unroll
            for (int s = 0; s < 8; ++s) tb[(it + 1) & 1][s] = rpn[s * 32];
        }

        float r = rr[it];
        const float* spL = &sFeat[wv][it][0] + h * 4;   // this half's v features
        float T0 = 0.0f;
        float T1x = 0.0f, T1y = 0.0f, T1z = 0.0f;
        float T2x = 0.0f, T2y = 0.0f, T2z = 0.0f;
        float T3x = 0.0f, T3y = 0.0f, T3z = 0.0f;
        #pragma unroll
        for (int s = 0; s < 8; ++s) {
            float4 t = tb[it & 1][s];   // {s01,s23,i01,i23} fp16-packed
            __half2 hs01 = bc_h2(t.x), hs23 = bc_h2(t.y);
            __half2 hi01 = bc_h2(t.z), hi23 = bc_h2(t.w);
            float R0 = fmaf(r, __low2float(hs01),  __low2float(hi01));
            float R1 = fmaf(r, __high2float(hs01), __high2float(hi01));
            float R2 = fmaf(r, __low2float(hs23),  __low2float(hi23));
            float R3 = fmaf(r, __high2float(hs23), __high2float(hi23));
            float4 fq = *(const float4*)&spL[s * 8];  // {f1x,f1y,f1z,f0} for v=2s+h
            T0  = fmaf(R0, fq.w, T0);
            T1x = fmaf(R1, fq.x, T1x);
            T1y = fmaf(R1, fq.y, T1y);
            T1z = fmaf(R1, fq.z, T1z);
            T2x = fmaf(R2, fq.x, T2x);
            T2y = fmaf(R2, fq.y, T2y);
            T2z = fmaf(R2, fq.z, T2z);
            T3x = fmaf(R3, fq.x, T3x);
            T3y = fmaf(R3, fq.y, T3y);
            T3z = fmaf(R3, fq.z, T3z);
        }

        // ---- per-task contraction (no cross-lane traffic) ----
        float nx = nxa[it], ny = nya[it], nz = nza[it];
        // real SH (e3nn convention; l=1 order y,z,x)
        float Y1_0 = c1sh * ny, Y1_1 = c1sh * nz, Y1_2 = c1sh * nx;
        float Y2_0 = c21 * nx * ny;
        float Y2_1 = c21 * ny * nz;
        float Y2_2 = c22 * fmaf(3.0f, nz * nz, -1.0f);
        float Y2_3 = c21 * nx * nz;
        float Y2_4 = c23 * (nx * nx - ny * ny);
        float za_ = is10 * Y2_0, zb_ = is10 * Y2_1, zc_ = is10 * Y2_3;
        float zd_ = is30 * Y2_2, ze_ = is10 * Y2_4;

        // l0 task: s = T0 + Y1.T1   (slots A,B; T2/T3 are zero)
        float sl0 = T0;
        sl0 = fmaf(Y1_0, T1x, sl0);
        sl0 = fmaf(Y1_1, T1y, sl0);
        sl0 = fmaf(Y1_2, T1z, sl0);

        // l1 task, output i: s_i = Y1_i*T0 + T1_i + cross_i(T2) + Z_i(T3)
        float sx = fmaf(Y1_0, T0, T1x);
        sx = fmaf(Y1_2, T2y, sx); sx = fmaf(-Y1_1, T2z, sx);
        sx = fmaf(-(zd_ + ze_), T3x, sx); sx = fmaf(zb_, T3y, sx); sx = fmaf(za_, T3z, sx);

        float sy = fmaf(Y1_1, T0, T1y);
        sy = fmaf(-Y1_2, T2x, sy); sy = fmaf(Y1_0, T2z, sy);
        sy = fmaf(zb_, T3x, sy); sy = fmaf(2.0f * zd_, T3y, sy); sy = fmaf(zc_, T3z, sy);

        float sz = fmaf(Y1_2, T0, T1z);
        sz = fmaf(Y1_1, T2x, sz); sz = fmaf(-Y1_0, T2y, sz);
        sz = fmaf(za_, T3x, sz); sz = fmaf(zc_, T3y, sz); sz = fmaf(ze_ - zd_, T3z, sz);

        float s0 = tl0 ? sl0 : sx;
        float zf = zfa[it];
        acc0 = fmaf(s0, zf, acc0);
        acc1 = fmaf(sy, zf, acc1);
        acc2 = fmaf(sz, zf, acc2);
    }

    // ---- combine the two v-halves: 3 shuffles total ----
    acc0 += __shfl_xor(acc0, 32);
    acc1 += __shfl_xor(acc1, 32);
    acc2 += __shfl_xor(acc2, 32);

    if (lane < 32) {
        if (tl0) {
            sAcc[wv][tu] = acc0;
        } else {
            int ob = 16 + tu * 3;
            sAcc[wv][ob]     = acc0;
            sAcc[wv][ob + 1] = acc1;
            sAcc[wv][ob + 2] = acc2;
        }
    }
    __syncthreads();
    if (threadIdx.x < 64) {
        float sum = sAcc[0][threadIdx.x] + sAcc[1][threadIdx.x]
                  + sAcc[2][threadIdx.x] + sAcc[3][threadIdx.x];
        sum *= mask[za];
        atomicAdd(&out[(size_t)za * 64 + threadIdx.x], sum);
    }
}

extern "C" void kernel_launch(void* const* d_in, const int* in_sizes, int n_in,
                              void* d_out, int out_size, void* d_ws, size_t ws_size,
                              hipStream_t stream) {
    (void)in_sizes; (void)n_in; (void)d_ws; (void)ws_size; (void)out_size;
    const float* feat = (const float*)d_in[0];
    const float* geom = (const float*)d_in[1];
    const float* mask = (const float*)d_in[2];
    const float* W1   = (const float*)d_in[3];
    const float* b1   = (const float*)d_in[4];
    const float* W2   = (const float*)d_in[5];
    const float* b2   = (const float*)d_in[6];
    float* out = (float*)d_out;

    k_prep<<<470, 256, 0, stream>>>(W1, b1, W2, b2, out);   // 390 table + 80 zero
    k_main<<<2 * NA * CW / 4, 256, 0, stream>>>(feat, geom, mask, out);
}